// Round 6
// baseline (317.785 us; speedup 1.0000x reference)
//
#include <hip/hip_runtime.h>

#define S_LEN    2048
#define D_MODEL  1024
#define N_HEADS  16
#define HEAD_DIM 64
#define BATCH    2

typedef __bf16 bf16x8 __attribute__((ext_vector_type(8)));
typedef float  floatx4 __attribute__((ext_vector_type(4)));

__device__ __forceinline__ unsigned short f2bf(float f) {
    union { float f; unsigned int u; } v;
    v.f = f;
    unsigned int u = v.u;
    u += 0x7fffu + ((u >> 16) & 1u);   // RNE
    return (unsigned short)(u >> 16);
}

// pack two floats to bf16 pair (a -> low, b -> high), RNE
__device__ __forceinline__ unsigned int pk_rne(float a, float b) {
    union { float f; unsigned int u; } ua, ub;
    ua.f = a; ub.f = b;
    unsigned int x = ua.u + 0x7fffu + ((ua.u >> 16) & 1u);
    unsigned int y = ub.u + 0x7fffu + ((ub.u >> 16) & 1u);
    return __builtin_amdgcn_perm(y, x, 0x07060302);  // low = x.hi16, high = y.hi16
}

__device__ __forceinline__ void gload_lds16(const unsigned short* g, unsigned short* l) {
    __builtin_amdgcn_global_load_lds(
        (const __attribute__((address_space(1))) void*)(const void*)g,
        (__attribute__((address_space(3))) void*)(void*)l,
        16, 0, 0);
}

#define LDS_FENCE() __asm__ volatile("s_waitcnt lgkmcnt(0)" ::: "memory")

// ---------- fused prep: fp32->bf16 for q,k,v  +  W[K][N] -> Wt[N][K] bf16 ----------
struct PrepArgs {
    const float* src[3]; unsigned short* dst[3];
    const float* W[4];   unsigned short* Wt[4];
};

#define CONV_BLOCKS (3 * 4096)

__global__ void prep_kernel(PrepArgs args) {
    const int bid = blockIdx.x;
    if (bid < CONV_BLOCKS) {
        const int t   = bid >> 12;
        const int blk = bid & 4095;
        const int i   = blk * 256 + threadIdx.x;
        float4 f = reinterpret_cast<const float4*>(args.src[t])[i];
        ushort4 o;
        o.x = f2bf(f.x); o.y = f2bf(f.y); o.z = f2bf(f.z); o.w = f2bf(f.w);
        reinterpret_cast<ushort4*>(args.dst[t])[i] = o;
    } else {
        __shared__ unsigned short tile[64][65];
        const int r  = bid - CONV_BLOCKS;
        const int w  = r >> 8;
        const int xy = r & 255;
        const int n0 = (xy & 15) * 64, k0 = (xy >> 4) * 64;
        const float* W = args.W[w];
        unsigned short* Wt = args.Wt[w];
        for (int rep = 0; rep < 16; ++rep) {
            int e = rep * 256 + threadIdx.x;
            int kk = e >> 6, nn = e & 63;
            tile[kk][nn] = f2bf(W[(size_t)(k0 + kk) * D_MODEL + n0 + nn]);
        }
        __syncthreads();
        for (int rep = 0; rep < 16; ++rep) {
            int e = rep * 256 + threadIdx.x;
            int nn = e >> 6, kk = e & 63;
            Wt[(size_t)(n0 + nn) * D_MODEL + k0 + kk] = tile[kk][nn];
        }
    }
}

// ---------- GEMM core: C[TM][TN] tile of A[M][1024] * Bt[N][1024]^T + bias ----------
// MODE 0: bf16 out [B,H,S,DK]   (operands swapped -> acc rows are n, cols m)
// MODE 1: bf16 out [B,H,DK,S]   (normal        -> acc rows are m, cols n)
// MODE 2: fp32 out [M][N]       (operands swapped)
// Epilogue: pack in-lane pairs -> per-wave LDS slice -> b128 coalesced stores.
template <int TM, int TN, int MODE>
__device__ __forceinline__
void gemm_body(const unsigned short* __restrict__ A,
               const unsigned short* __restrict__ Bt,
               const float* __restrict__ bias,
               void* __restrict__ out,
               int m0, int n0, float scale,
               unsigned short* smem) {
    constexpr int MT = TM / 32;
    constexpr int NT = TN / 32;
    unsigned short* As = smem;
    unsigned short* Bs = smem + TM * 32;
    const int tid  = threadIdx.x;
    const int wid  = tid >> 6;
    const int lane = tid & 63;

    floatx4 acc[MT][NT];
#pragma unroll
    for (int i = 0; i < MT; ++i)
#pragma unroll
        for (int j = 0; j < NT; ++j) acc[i][j] = (floatx4)0.0f;

    const int srow = lane >> 2;
    const int gch  = (lane & 3) ^ ((srow >> 1) & 3);
    const int wr = (wid >> 1) * (TM / 2);
    const int wc = (wid & 1) * (TN / 2);
    const int fr = lane & 15;
    const int fq = lane >> 4;
    const int swz = (fq ^ ((fr >> 1) & 3)) * 8;

    for (int k0 = 0; k0 < D_MODEL; k0 += 32) {
        if (k0) __syncthreads();
#pragma unroll
        for (int ci = 0; ci < (TM + TN) / 64; ++ci) {
            const int c = wid + ci * 4;
            if (c < TM / 16) {
                const int row = c * 16 + srow;
                gload_lds16(A + (size_t)(m0 + row) * D_MODEL + k0 + gch * 8, As + c * 512);
            } else {
                const int cb = c - TM / 16;
                const int row = cb * 16 + srow;
                gload_lds16(Bt + (size_t)(n0 + row) * D_MODEL + k0 + gch * 8, Bs + cb * 512);
            }
        }
        __syncthreads();

        bf16x8 af[MT], bfv[NT];
#pragma unroll
        for (int t = 0; t < MT; ++t)
            af[t] = *reinterpret_cast<const bf16x8*>(As + (wr + t * 16 + fr) * 32 + swz);
#pragma unroll
        for (int t = 0; t < NT; ++t)
            bfv[t] = *reinterpret_cast<const bf16x8*>(Bs + (wc + t * 16 + fr) * 32 + swz);
#pragma unroll
        for (int mt = 0; mt < MT; ++mt)
#pragma unroll
            for (int nt = 0; nt < NT; ++nt) {
                if (MODE == 1)
                    acc[mt][nt] = __builtin_amdgcn_mfma_f32_16x16x32_bf16(af[mt], bfv[nt], acc[mt][nt], 0, 0, 0);
                else
                    acc[mt][nt] = __builtin_amdgcn_mfma_f32_16x16x32_bf16(bfv[nt], af[mt], acc[mt][nt], 0, 0, 0);
            }
    }

    __syncthreads();  // staging LDS is about to be reused for the store repack

    if (MODE == 0) {
        // acc rows = n-local (nt*16 + fq*4 + r), cols = m-local (mt*16 + fr)
        unsigned short* rp = smem + wid * 1024;   // [16 m][64 n] bf16 slice
        unsigned short* outbf = (unsigned short*)out;
        float4 b4[NT];
#pragma unroll
        for (int nt = 0; nt < NT; ++nt)
            b4[nt] = *reinterpret_cast<const float4*>(bias + n0 + wc + nt * 16 + fq * 4);
        const int hh = (n0 + wc) >> 6;
#pragma unroll
        for (int mt = 0; mt < MT; ++mt) {
#pragma unroll
            for (int nt = 0; nt < NT; ++nt) {
                const float* bb = reinterpret_cast<const float*>(&b4[nt]);
#pragma unroll
                for (int p = 0; p < 2; ++p) {
                    float v0 = (acc[mt][nt][2 * p]     + bb[2 * p])     * scale;
                    float v1 = (acc[mt][nt][2 * p + 1] + bb[2 * p + 1]) * scale;
                    *reinterpret_cast<unsigned int*>(rp + fr * 64 + nt * 16 + fq * 4 + 2 * p) = pk_rne(v0, v1);
                }
            }
            LDS_FENCE();
#pragma unroll
            for (int j = 0; j < 2; ++j) {
                const int row = (lane >> 3) + j * 8;
                const int m = m0 + wr + mt * 16 + row;
                const int b = m >> 11, s = m & (S_LEN - 1);
                uint4 val = *reinterpret_cast<const uint4*>(rp + row * 64 + (lane & 7) * 8);
                *reinterpret_cast<uint4*>(outbf + (((size_t)(b * N_HEADS + hh) * S_LEN + s) * HEAD_DIM) + (lane & 7) * 8) = val;
            }
            LDS_FENCE();
        }
    } else if (MODE == 1) {
        // acc rows = m-local (mt*16 + fq*4 + r), cols = n-local (nt*16 + fr)
        unsigned short* rp = smem + wid * 1024;   // [16 n][64 m] bf16 slice
        unsigned short* outbf = (unsigned short*)out;
        float bval[NT];
#pragma unroll
        for (int nt = 0; nt < NT; ++nt) bval[nt] = bias[n0 + wc + nt * 16 + fr];
#pragma unroll
        for (int nt = 0; nt < NT; ++nt) {
#pragma unroll
            for (int mt = 0; mt < MT; ++mt) {
#pragma unroll
                for (int p = 0; p < 2; ++p) {
                    float v0 = acc[mt][nt][2 * p]     + bval[nt];
                    float v1 = acc[mt][nt][2 * p + 1] + bval[nt];
                    *reinterpret_cast<unsigned int*>(rp + fr * 64 + mt * 16 + fq * 4 + 2 * p) = pk_rne(v0, v1);
                }
            }
            LDS_FENCE();
#pragma unroll
            for (int j = 0; j < 2; ++j) {
                const int row = (lane >> 3) + j * 8;
                const int n = n0 + wc + nt * 16 + row;
                const int h = n >> 6, dk = n & 63;
                const int mch = m0 + wr + (lane & 7) * 8;
                const int b = mch >> 11, s = mch & (S_LEN - 1);
                uint4 val = *reinterpret_cast<const uint4*>(rp + row * 64 + (lane & 7) * 8);
                *reinterpret_cast<uint4*>(outbf + ((size_t)(b * N_HEADS + h) * HEAD_DIM + dk) * S_LEN + s) = val;
            }
            LDS_FENCE();
        }
    } else {
        // MODE 2: acc rows = n-local, cols = m-local; fp32 out [M][1024]
        float* rpf = reinterpret_cast<float*>(smem) + wid * 1024;  // [16 m][64 n] fp32 slice
        float* outf = (float*)out;
        float4 b4[NT];
#pragma unroll
        for (int nt = 0; nt < NT; ++nt)
            b4[nt] = *reinterpret_cast<const float4*>(bias + n0 + wc + nt * 16 + fq * 4);
#pragma unroll
        for (int mt = 0; mt < MT; ++mt) {
#pragma unroll
            for (int nt = 0; nt < NT; ++nt) {
                const float* bb = reinterpret_cast<const float*>(&b4[nt]);
#pragma unroll
                for (int p = 0; p < 2; ++p) {
                    float2 w;
                    w.x = acc[mt][nt][2 * p]     + bb[2 * p];
                    w.y = acc[mt][nt][2 * p + 1] + bb[2 * p + 1];
                    *reinterpret_cast<float2*>(rpf + fr * 64 + nt * 16 + fq * 4 + 2 * p) = w;
                }
            }
            LDS_FENCE();
#pragma unroll
            for (int j = 0; j < 4; ++j) {
                const int row = (lane >> 4) + j * 4;
                const int m = m0 + wr + mt * 16 + row;
                float4 val = *reinterpret_cast<const float4*>(rpf + row * 64 + (lane & 15) * 4);
                *reinterpret_cast<float4*>(outf + (size_t)m * D_MODEL + n0 + wc + (lane & 15) * 4) = val;
            }
            LDS_FENCE();
        }
    }
}

// fused Q/K/V projection
struct QKVArgs {
    const unsigned short* A[3];
    const unsigned short* Bt[3];
    const float* bias[3];
    unsigned short* out[3];
};

__global__ __launch_bounds__(256)
void qkv_gemm_kernel(QKVArgs args) {
    __shared__ __align__(16) unsigned short smem[8192];
    const int z = blockIdx.z;
    const int m0 = blockIdx.y * 128;
    const int n0 = blockIdx.x * 128;
    // Q gets 0.125*log2(e) folded in so attention uses raw exp2
    if (z == 0)
        gemm_body<128, 128, 0>(args.A[0], args.Bt[0], args.bias[0], args.out[0], m0, n0, 0.18033688011112f, smem);
    else if (z == 1)
        gemm_body<128, 128, 0>(args.A[1], args.Bt[1], args.bias[1], args.out[1], m0, n0, 1.0f, smem);
    else
        gemm_body<128, 128, 1>(args.A[2], args.Bt[2], args.bias[2], args.out[2], m0, n0, 1.0f, smem);
}

// O projection: 64x128 tiles -> 512 blocks
__global__ __launch_bounds__(256)
void oproj_gemm_kernel(const unsigned short* __restrict__ A,
                       const unsigned short* __restrict__ Bt,
                       const float* __restrict__ bias,
                       float* __restrict__ out) {
    __shared__ __align__(16) unsigned short smem[8192];
    gemm_body<64, 128, 2>(A, Bt, bias, out, blockIdx.y * 64, blockIdx.x * 128, 1.0f, smem);
}

// ---------- attention: zero-barrier, all-register K/V ----------
// 1 wave per block, 32 q rows per wave (2 subtiles of 16). K and V^T fragments load
// DIRECTLY global->registers (16 x b128 per 64-kv tile, fully contiguous) -- no LDS
// staging, no __syncthreads anywhere. Row-sum l via MFMA with an all-ones B... A operand.
// PV uses swapped operands so O lands with d in-lane -> packed pairs -> LDS repack ->
// 4 x b128 coalesced stores. P round-trips through a wave-private 4.6 KB LDS buffer.
__global__ __launch_bounds__(64)
void attn_kernel(const unsigned short* __restrict__ qhp,
                 const unsigned short* __restrict__ khp,
                 const unsigned short* __restrict__ vtp,
                 unsigned short* __restrict__ outp) {
    __shared__ __align__(16) unsigned short Ps[32 * 72];  // [q_local][kv] / reused for O repack

    const int lane = threadIdx.x;
    const int b = blockIdx.z, h = blockIdx.y;
    const int q0 = blockIdx.x * 32;

    const unsigned short* qbase = qhp + (size_t)(b * N_HEADS + h) * S_LEN * HEAD_DIM;
    const unsigned short* kbase = khp + (size_t)(b * N_HEADS + h) * S_LEN * HEAD_DIM;
    const unsigned short* vbase = vtp + (size_t)(b * N_HEADS + h) * HEAD_DIM * S_LEN;

    const int fr = lane & 15;
    const int fq = lane >> 4;

    // Q B-operand fragments (persistent): B[n=q=fr][k = dk chunk fq*8]
    bf16x8 qf[2][2];
#pragma unroll
    for (int qh2 = 0; qh2 < 2; ++qh2)
#pragma unroll
        for (int kk = 0; kk < 2; ++kk)
            qf[qh2][kk] = *reinterpret_cast<const bf16x8*>(
                qbase + (size_t)(q0 + qh2 * 16 + fr) * HEAD_DIM + (kk * 4 + fq) * 8);

    bf16x8 ones;
#pragma unroll
    for (int i = 0; i < 8; ++i) ones[i] = (__bf16)1.0f;

    floatx4 o_acc[2][4];
#pragma unroll
    for (int i = 0; i < 2; ++i)
#pragma unroll
        for (int j = 0; j < 4; ++j) o_acc[i][j] = (floatx4)0.0f;
    floatx4 l_acc[2];
    l_acc[0] = (floatx4)0.0f; l_acc[1] = (floatx4)0.0f;

    for (int it = 0; it < S_LEN / 64; ++it) {
        const int kv0 = it * 64;

        // K rows (A-operand: m=kv-local=fr, k=dk chunk) and V^T rows (A-operand for
        // swapped PV: m=d=fr, k=kv chunk) -- all direct global b128 loads.
        bf16x8 kf[4][2], vf[4][2];
#pragma unroll
        for (int nt = 0; nt < 4; ++nt)
#pragma unroll
            for (int kk = 0; kk < 2; ++kk)
                kf[nt][kk] = *reinterpret_cast<const bf16x8*>(
                    kbase + (size_t)(kv0 + nt * 16 + fr) * HEAD_DIM + (kk * 4 + fq) * 8);
#pragma unroll
        for (int dt = 0; dt < 4; ++dt)
#pragma unroll
            for (int kk = 0; kk < 2; ++kk)
                vf[dt][kk] = *reinterpret_cast<const bf16x8*>(
                    vbase + (size_t)(dt * 16 + fr) * S_LEN + kv0 + (kk * 4 + fq) * 8);

        // S^T = K Q^T : D[m=kv][n=q]; col=fr=q, rows fq*4+r = kv-local
        floatx4 st[2][4];
#pragma unroll
        for (int i = 0; i < 2; ++i)
#pragma unroll
            for (int j = 0; j < 4; ++j) st[i][j] = (floatx4)0.0f;
#pragma unroll
        for (int nt = 0; nt < 4; ++nt)
#pragma unroll
            for (int kk = 0; kk < 2; ++kk) {
                st[0][nt] = __builtin_amdgcn_mfma_f32_16x16x32_bf16(kf[nt][kk], qf[0][kk], st[0][nt], 0, 0, 0);
                st[1][nt] = __builtin_amdgcn_mfma_f32_16x16x32_bf16(kf[nt][kk], qf[1][kk], st[1][nt], 0, 0, 0);
            }

        // P = exp2(S^T); lane holds P[q=fr][kv = nt*16 + fq*4 + r]
#pragma unroll
        for (int qh2 = 0; qh2 < 2; ++qh2)
#pragma unroll
            for (int nt = 0; nt < 4; ++nt) {
                float p0 = __builtin_amdgcn_exp2f(st[qh2][nt][0]);
                float p1 = __builtin_amdgcn_exp2f(st[qh2][nt][1]);
                float p2 = __builtin_amdgcn_exp2f(st[qh2][nt][2]);
                float p3 = __builtin_amdgcn_exp2f(st[qh2][nt][3]);
                uint2 w;
                w.x = pk_rne(p0, p1);
                w.y = pk_rne(p2, p3);
                *reinterpret_cast<uint2*>(Ps + (qh2 * 16 + fr) * 72 + nt * 16 + fq * 4) = w;
            }
        LDS_FENCE();  // wave-local write->read ordering

        // P A/B fragments: B[n=q=fr][k=kv chunk kk*32+fq*8]
#pragma unroll
        for (int kk = 0; kk < 2; ++kk) {
            bf16x8 pf0 = *reinterpret_cast<const bf16x8*>(Ps + (fr)      * 72 + kk * 32 + fq * 8);
            bf16x8 pf1 = *reinterpret_cast<const bf16x8*>(Ps + (16 + fr) * 72 + kk * 32 + fq * 8);
            // l += ones * P  (cols = q; every row identical)
            l_acc[0] = __builtin_amdgcn_mfma_f32_16x16x32_bf16(ones, pf0, l_acc[0], 0, 0, 0);
            l_acc[1] = __builtin_amdgcn_mfma_f32_16x16x32_bf16(ones, pf1, l_acc[1], 0, 0, 0);
            // O^T: D[m=d][n=q] = V^T * P^T-ish via swapped operands
#pragma unroll
            for (int dt = 0; dt < 4; ++dt) {
                o_acc[0][dt] = __builtin_amdgcn_mfma_f32_16x16x32_bf16(vf[dt][kk], pf0, o_acc[0][dt], 0, 0, 0);
                o_acc[1][dt] = __builtin_amdgcn_mfma_f32_16x16x32_bf16(vf[dt][kk], pf1, o_acc[1][dt], 0, 0, 0);
            }
        }
    }

    // epilogue: o_acc[qh2][dt]: rows = d-local (fq*4+r within dt*16), col = q = fr.
    // linv for q=fr is broadcast in l_acc (any row).
#pragma unroll
    for (int qh2 = 0; qh2 < 2; ++qh2) {
        const float linv = __builtin_amdgcn_rcpf(l_acc[qh2][0]);
#pragma unroll
        for (int dt = 0; dt < 4; ++dt)
#pragma unroll
            for (int p = 0; p < 2; ++p) {
                float v0 = o_acc[qh2][dt][2 * p]     * linv;
                float v1 = o_acc[qh2][dt][2 * p + 1] * linv;
                *reinterpret_cast<unsigned int*>(
                    Ps + (qh2 * 16 + fr) * 72 + dt * 16 + fq * 4 + 2 * p) = pk_rne(v0, v1);
            }
    }
    LDS_FENCE();
#pragma unroll
    for (int j = 0; j < 4; ++j) {
        const int row = (lane >> 3) + j * 8;     // q_local 0..31
        const int s = q0 + row;
        uint4 val = *reinterpret_cast<const uint4*>(Ps + row * 72 + (lane & 7) * 8);
        *reinterpret_cast<uint4*>(outp + ((size_t)(b * S_LEN + s)) * D_MODEL + h * HEAD_DIM + (lane & 7) * 8) = val;
    }
}

extern "C" void kernel_launch(void* const* d_in, const int* in_sizes, int n_in,
                              void* d_out, int out_size, void* d_ws, size_t ws_size,
                              hipStream_t stream) {
    (void)in_sizes; (void)n_in; (void)out_size; (void)ws_size;
    const float* q  = (const float*)d_in[0];
    const float* k  = (const float*)d_in[1];
    const float* v  = (const float*)d_in[2];
    // d_in[3] = mask: mathematical no-op in the reference
    const float* Wq = (const float*)d_in[4];
    const float* bq = (const float*)d_in[5];
    const float* Wk = (const float*)d_in[6];
    const float* bk = (const float*)d_in[7];
    const float* Wv = (const float*)d_in[8];
    const float* bv = (const float*)d_in[9];
    const float* Wo = (const float*)d_in[10];
    const float* bo = (const float*)d_in[11];
    float* out = (float*)d_out;

    char* ws = (char*)d_ws;
    const size_t SZ_ACT = (size_t)BATCH * S_LEN * D_MODEL * 2;  // 8 MB
    const size_t SZ_W   = (size_t)D_MODEL * D_MODEL * 2;        // 2 MB
    unsigned short* qb   = (unsigned short*)(ws);
    unsigned short* kb   = (unsigned short*)(ws + SZ_ACT);
    unsigned short* vb   = (unsigned short*)(ws + 2 * SZ_ACT);
    unsigned short* Wqt  = (unsigned short*)(ws + 3 * SZ_ACT);
    unsigned short* Wkt  = (unsigned short*)(ws + 3 * SZ_ACT + SZ_W);
    unsigned short* Wvt  = (unsigned short*)(ws + 3 * SZ_ACT + 2 * SZ_W);
    unsigned short* Wot  = (unsigned short*)(ws + 3 * SZ_ACT + 3 * SZ_W);
    unsigned short* qhb  = (unsigned short*)(ws + 3 * SZ_ACT + 4 * SZ_W);
    unsigned short* khb  = (unsigned short*)(ws + 4 * SZ_ACT + 4 * SZ_W);
    unsigned short* vtb  = (unsigned short*)(ws + 5 * SZ_ACT + 4 * SZ_W);
    unsigned short* attn = qb;  // qb dead after Q projection

    PrepArgs pargs;
    pargs.src[0] = q;  pargs.src[1] = k;  pargs.src[2] = v;
    pargs.dst[0] = qb; pargs.dst[1] = kb; pargs.dst[2] = vb;
    pargs.W[0] = Wq;  pargs.W[1] = Wk;  pargs.W[2] = Wv;  pargs.W[3] = Wo;
    pargs.Wt[0] = Wqt; pargs.Wt[1] = Wkt; pargs.Wt[2] = Wvt; pargs.Wt[3] = Wot;
    prep_kernel<<<dim3(CONV_BLOCKS + 1024), 256, 0, stream>>>(pargs);

    QKVArgs gargs;
    gargs.A[0] = qb;  gargs.A[1] = kb;  gargs.A[2] = vb;
    gargs.Bt[0] = Wqt; gargs.Bt[1] = Wkt; gargs.Bt[2] = Wvt;
    gargs.bias[0] = bq; gargs.bias[1] = bk; gargs.bias[2] = bv;
    gargs.out[0] = qhb; gargs.out[1] = khb; gargs.out[2] = vtb;
    qkv_gemm_kernel<<<dim3(8, 32, 3), 256, 0, stream>>>(gargs);

    attn_kernel<<<dim3(S_LEN / 32, N_HEADS, BATCH), 64, 0, stream>>>(qhb, khb, vtb, attn);

    oproj_gemm_kernel<<<dim3(8, 64), 256, 0, stream>>>(attn, Wot, bo, out);
}

// Round 7
// 259.684 us; speedup vs baseline: 1.2237x; 1.2237x over previous
//
#include <hip/hip_runtime.h>

#define S_LEN    2048
#define D_MODEL  1024
#define N_HEADS  16
#define HEAD_DIM 64
#define BATCH    2

typedef __bf16 bf16x8 __attribute__((ext_vector_type(8)));
typedef float  floatx4 __attribute__((ext_vector_type(4)));
typedef float  floatx16 __attribute__((ext_vector_type(16)));

__device__ __forceinline__ unsigned short f2bf(float f) {
    union { float f; unsigned int u; } v;
    v.f = f;
    unsigned int u = v.u;
    u += 0x7fffu + ((u >> 16) & 1u);   // RNE
    return (unsigned short)(u >> 16);
}

// pack two floats to bf16 pair (a -> low, b -> high), RNE
__device__ __forceinline__ unsigned int pk_rne(float a, float b) {
    union { float f; unsigned int u; } ua, ub;
    ua.f = a; ub.f = b;
    unsigned int x = ua.u + 0x7fffu + ((ua.u >> 16) & 1u);
    unsigned int y = ub.u + 0x7fffu + ((ub.u >> 16) & 1u);
    return __builtin_amdgcn_perm(y, x, 0x07060302);  // low = x.hi16, high = y.hi16
}

__device__ __forceinline__ void gload_lds16(const unsigned short* g, unsigned short* l) {
    __builtin_amdgcn_global_load_lds(
        (const __attribute__((address_space(1))) void*)(const void*)g,
        (__attribute__((address_space(3))) void*)(void*)l,
        16, 0, 0);
}

#define LDS_FENCE() __asm__ volatile("s_waitcnt lgkmcnt(0)" ::: "memory")

// ---------- fused prep: fp32->bf16 for q,k,v  +  W[K][N] -> Wt[N][K] bf16 ----------
struct PrepArgs {
    const float* src[3]; unsigned short* dst[3];
    const float* W[4];   unsigned short* Wt[4];
};

#define CONV_BLOCKS (3 * 4096)

__global__ void prep_kernel(PrepArgs args) {
    const int bid = blockIdx.x;
    if (bid < CONV_BLOCKS) {
        const int t   = bid >> 12;
        const int blk = bid & 4095;
        const int i   = blk * 256 + threadIdx.x;
        float4 f = reinterpret_cast<const float4*>(args.src[t])[i];
        ushort4 o;
        o.x = f2bf(f.x); o.y = f2bf(f.y); o.z = f2bf(f.z); o.w = f2bf(f.w);
        reinterpret_cast<ushort4*>(args.dst[t])[i] = o;
    } else {
        __shared__ unsigned short tile[64][65];
        const int r  = bid - CONV_BLOCKS;
        const int w  = r >> 8;
        const int xy = r & 255;
        const int n0 = (xy & 15) * 64, k0 = (xy >> 4) * 64;
        const float* W = args.W[w];
        unsigned short* Wt = args.Wt[w];
        for (int rep = 0; rep < 16; ++rep) {
            int e = rep * 256 + threadIdx.x;
            int kk = e >> 6, nn = e & 63;
            tile[kk][nn] = f2bf(W[(size_t)(k0 + kk) * D_MODEL + n0 + nn]);
        }
        __syncthreads();
        for (int rep = 0; rep < 16; ++rep) {
            int e = rep * 256 + threadIdx.x;
            int nn = e >> 6, kk = e & 63;
            Wt[(size_t)(n0 + nn) * D_MODEL + k0 + kk] = tile[kk][nn];
        }
    }
}

// ---------- GEMM core (unchanged from round 6; passed) ----------
template <int TM, int TN, int MODE>
__device__ __forceinline__
void gemm_body(const unsigned short* __restrict__ A,
               const unsigned short* __restrict__ Bt,
               const float* __restrict__ bias,
               void* __restrict__ out,
               int m0, int n0, float scale,
               unsigned short* smem) {
    constexpr int MT = TM / 32;
    constexpr int NT = TN / 32;
    unsigned short* As = smem;
    unsigned short* Bs = smem + TM * 32;
    const int tid  = threadIdx.x;
    const int wid  = tid >> 6;
    const int lane = tid & 63;

    floatx4 acc[MT][NT];
#pragma unroll
    for (int i = 0; i < MT; ++i)
#pragma unroll
        for (int j = 0; j < NT; ++j) acc[i][j] = (floatx4)0.0f;

    const int srow = lane >> 2;
    const int gch  = (lane & 3) ^ ((srow >> 1) & 3);
    const int wr = (wid >> 1) * (TM / 2);
    const int wc = (wid & 1) * (TN / 2);
    const int fr = lane & 15;
    const int fq = lane >> 4;
    const int swz = (fq ^ ((fr >> 1) & 3)) * 8;

    for (int k0 = 0; k0 < D_MODEL; k0 += 32) {
        if (k0) __syncthreads();
#pragma unroll
        for (int ci = 0; ci < (TM + TN) / 64; ++ci) {
            const int c = wid + ci * 4;
            if (c < TM / 16) {
                const int row = c * 16 + srow;
                gload_lds16(A + (size_t)(m0 + row) * D_MODEL + k0 + gch * 8, As + c * 512);
            } else {
                const int cb = c - TM / 16;
                const int row = cb * 16 + srow;
                gload_lds16(Bt + (size_t)(n0 + row) * D_MODEL + k0 + gch * 8, Bs + cb * 512);
            }
        }
        __syncthreads();

        bf16x8 af[MT], bfv[NT];
#pragma unroll
        for (int t = 0; t < MT; ++t)
            af[t] = *reinterpret_cast<const bf16x8*>(As + (wr + t * 16 + fr) * 32 + swz);
#pragma unroll
        for (int t = 0; t < NT; ++t)
            bfv[t] = *reinterpret_cast<const bf16x8*>(Bs + (wc + t * 16 + fr) * 32 + swz);
#pragma unroll
        for (int mt = 0; mt < MT; ++mt)
#pragma unroll
            for (int nt = 0; nt < NT; ++nt) {
                if (MODE == 1)
                    acc[mt][nt] = __builtin_amdgcn_mfma_f32_16x16x32_bf16(af[mt], bfv[nt], acc[mt][nt], 0, 0, 0);
                else
                    acc[mt][nt] = __builtin_amdgcn_mfma_f32_16x16x32_bf16(bfv[nt], af[mt], acc[mt][nt], 0, 0, 0);
            }
    }

    __syncthreads();  // staging LDS reused for store repack

    if (MODE == 0) {
        unsigned short* rp = smem + wid * 1024;
        unsigned short* outbf = (unsigned short*)out;
        float4 b4[NT];
#pragma unroll
        for (int nt = 0; nt < NT; ++nt)
            b4[nt] = *reinterpret_cast<const float4*>(bias + n0 + wc + nt * 16 + fq * 4);
        const int hh = (n0 + wc) >> 6;
#pragma unroll
        for (int mt = 0; mt < MT; ++mt) {
#pragma unroll
            for (int nt = 0; nt < NT; ++nt) {
                const float* bb = reinterpret_cast<const float*>(&b4[nt]);
#pragma unroll
                for (int p = 0; p < 2; ++p) {
                    float v0 = (acc[mt][nt][2 * p]     + bb[2 * p])     * scale;
                    float v1 = (acc[mt][nt][2 * p + 1] + bb[2 * p + 1]) * scale;
                    *reinterpret_cast<unsigned int*>(rp + fr * 64 + nt * 16 + fq * 4 + 2 * p) = pk_rne(v0, v1);
                }
            }
            LDS_FENCE();
#pragma unroll
            for (int j = 0; j < 2; ++j) {
                const int row = (lane >> 3) + j * 8;
                const int m = m0 + wr + mt * 16 + row;
                const int b = m >> 11, s = m & (S_LEN - 1);
                uint4 val = *reinterpret_cast<const uint4*>(rp + row * 64 + (lane & 7) * 8);
                *reinterpret_cast<uint4*>(outbf + (((size_t)(b * N_HEADS + hh) * S_LEN + s) * HEAD_DIM) + (lane & 7) * 8) = val;
            }
            LDS_FENCE();
        }
    } else if (MODE == 1) {
        unsigned short* rp = smem + wid * 1024;
        unsigned short* outbf = (unsigned short*)out;
        float bval[NT];
#pragma unroll
        for (int nt = 0; nt < NT; ++nt) bval[nt] = bias[n0 + wc + nt * 16 + fr];
#pragma unroll
        for (int nt = 0; nt < NT; ++nt) {
#pragma unroll
            for (int mt = 0; mt < MT; ++mt) {
#pragma unroll
                for (int p = 0; p < 2; ++p) {
                    float v0 = acc[mt][nt][2 * p]     + bval[nt];
                    float v1 = acc[mt][nt][2 * p + 1] + bval[nt];
                    *reinterpret_cast<unsigned int*>(rp + fr * 64 + mt * 16 + fq * 4 + 2 * p) = pk_rne(v0, v1);
                }
            }
            LDS_FENCE();
#pragma unroll
            for (int j = 0; j < 2; ++j) {
                const int row = (lane >> 3) + j * 8;
                const int n = n0 + wc + nt * 16 + row;
                const int h = n >> 6, dk = n & 63;
                const int mch = m0 + wr + (lane & 7) * 8;
                const int b = mch >> 11, s = mch & (S_LEN - 1);
                uint4 val = *reinterpret_cast<const uint4*>(rp + row * 64 + (lane & 7) * 8);
                *reinterpret_cast<uint4*>(outbf + ((size_t)(b * N_HEADS + h) * HEAD_DIM + dk) * S_LEN + s) = val;
            }
            LDS_FENCE();
        }
    } else {
        float* rpf = reinterpret_cast<float*>(smem) + wid * 1024;
        float* outf = (float*)out;
        float4 b4[NT];
#pragma unroll
        for (int nt = 0; nt < NT; ++nt)
            b4[nt] = *reinterpret_cast<const float4*>(bias + n0 + wc + nt * 16 + fq * 4);
#pragma unroll
        for (int mt = 0; mt < MT; ++mt) {
#pragma unroll
            for (int nt = 0; nt < NT; ++nt) {
                const float* bb = reinterpret_cast<const float*>(&b4[nt]);
#pragma unroll
                for (int p = 0; p < 2; ++p) {
                    float2 w;
                    w.x = acc[mt][nt][2 * p]     + bb[2 * p];
                    w.y = acc[mt][nt][2 * p + 1] + bb[2 * p + 1];
                    *reinterpret_cast<float2*>(rpf + fr * 64 + nt * 16 + fq * 4 + 2 * p) = w;
                }
            }
            LDS_FENCE();
#pragma unroll
            for (int j = 0; j < 4; ++j) {
                const int row = (lane >> 4) + j * 4;
                const int m = m0 + wr + mt * 16 + row;
                float4 val = *reinterpret_cast<const float4*>(rpf + row * 64 + (lane & 15) * 4);
                *reinterpret_cast<float4*>(outf + (size_t)m * D_MODEL + n0 + wc + (lane & 15) * 4) = val;
            }
            LDS_FENCE();
        }
    }
}

struct QKVArgs {
    const unsigned short* A[3];
    const unsigned short* Bt[3];
    const float* bias[3];
    unsigned short* out[3];
};

__global__ __launch_bounds__(256)
void qkv_gemm_kernel(QKVArgs args) {
    __shared__ __align__(16) unsigned short smem[8192];
    const int z = blockIdx.z;
    const int m0 = blockIdx.y * 128;
    const int n0 = blockIdx.x * 128;
    if (z == 0)
        gemm_body<128, 128, 0>(args.A[0], args.Bt[0], args.bias[0], args.out[0], m0, n0, 0.18033688011112f, smem);
    else if (z == 1)
        gemm_body<128, 128, 0>(args.A[1], args.Bt[1], args.bias[1], args.out[1], m0, n0, 1.0f, smem);
    else
        gemm_body<128, 128, 1>(args.A[2], args.Bt[2], args.bias[2], args.out[2], m0, n0, 1.0f, smem);
}

__global__ __launch_bounds__(256)
void oproj_gemm_kernel(const unsigned short* __restrict__ A,
                       const unsigned short* __restrict__ Bt,
                       const float* __restrict__ bias,
                       float* __restrict__ out) {
    __shared__ __align__(16) unsigned short smem[8192];
    gemm_body<64, 128, 2>(A, Bt, bias, out, blockIdx.y * 64, blockIdx.x * 128, 1.0f, smem);
}

// ---------- attention: 32x32 MFMA framework, register P-transform ----------
// 256 threads (4 waves), 128 q/block, 32 q/wave, BK=128 kv per barrier-iter.
// S^T = K Q^T via 32x32x16 (D col = q = lane&31). The PV B-operand layout
// (B[n=q][k=half*8+j]) is reached IN REGISTERS: pack exp pairs, one
// shfl_xor(32) per dword, cndmask-by-half. No P LDS roundtrip, no full
// lgkmcnt fences, no Ps buffer. K/V staged in LDS (XOR-swizzled, shared by
// all 4 waves). l accumulates per lane (q-resident) + one shfl_xor(32).
__global__ __launch_bounds__(256)
void attn_kernel(const unsigned short* __restrict__ qhp,
                 const unsigned short* __restrict__ khp,
                 const unsigned short* __restrict__ vtp,
                 unsigned short* __restrict__ outp) {
    __shared__ __align__(16) unsigned short Ks[128 * 64];   // [kv][dk]   swizzled
    __shared__ __align__(16) unsigned short Vs[64 * 128];   // [d][kv]    swizzled

    const int tid  = threadIdx.x;
    const int wid  = tid >> 6;
    const int lane = tid & 63;
    const int b = blockIdx.z, h = blockIdx.y;
    const int q0 = blockIdx.x * 128;
    const int q31  = lane & 31;
    const int half = lane >> 5;

    const unsigned short* qbase = qhp + (size_t)(b * N_HEADS + h) * S_LEN * HEAD_DIM;
    const unsigned short* kbase = khp + (size_t)(b * N_HEADS + h) * S_LEN * HEAD_DIM;
    const unsigned short* vbase = vtp + (size_t)(b * N_HEADS + h) * HEAD_DIM * S_LEN;

    // persistent Q B-operand frags: B[n=q][k = kc*16 + half*8 + j]
    bf16x8 qf[4];
#pragma unroll
    for (int kc = 0; kc < 4; ++kc)
        qf[kc] = *reinterpret_cast<const bf16x8*>(
            qbase + (size_t)(q0 + wid * 32 + q31) * HEAD_DIM + kc * 16 + half * 8);

    floatx16 o_acc[2];
    o_acc[0] = (floatx16)0.0f; o_acc[1] = (floatx16)0.0f;
    float l_part = 0.0f;

    const int srow  = lane >> 3;            // 0..7   (K staging)
    const int gch   = (lane & 7) ^ srow;    // K: swizzled 16B chunk in 128B row
    const int srow4 = lane >> 4;            // 0..3   (V staging)

    for (int it = 0; it < S_LEN / 128; ++it) {
        const int kv0 = it * 128;
        __syncthreads();   // all waves done reading previous tile
#pragma unroll
        for (int i = 0; i < 4; ++i) {
            const int c = wid * 4 + i;
            const int krow = c * 8 + srow;                    // 0..127
            gload_lds16(kbase + (size_t)(kv0 + krow) * HEAD_DIM + gch * 8, Ks + c * 512);
            const int vrow = c * 4 + srow4;                   // 0..63
            const int gchv = (lane & 15) ^ (vrow & 7);
            gload_lds16(vbase + (size_t)vrow * S_LEN + kv0 + gchv * 8, Vs + c * 512);
        }
        __syncthreads();   // staging complete

#pragma unroll
        for (int mt = 0; mt < 4; ++mt) {
            // K A-frags: A[m = kv-local][k = kc*16 + half*8 + j]
            const int krow = mt * 32 + q31;
            const int ksw  = krow & 7;
            floatx16 st = (floatx16)0.0f;
#pragma unroll
            for (int kc = 0; kc < 4; ++kc) {
                bf16x8 kf = *reinterpret_cast<const bf16x8*>(
                    Ks + krow * 64 + (((kc * 2 + half) ^ ksw) * 8));
                st = __builtin_amdgcn_mfma_f32_32x32x16_bf16(kf, qf[kc], st, 0, 0, 0);
            }

            // P = exp2(S^T): lane holds P[q=q31][kv = (r&3) + 8*(r>>2) + 4*half]
            float p[16];
#pragma unroll
            for (int r = 0; r < 16; ++r) p[r] = __builtin_amdgcn_exp2f(st[r]);
#pragma unroll
            for (int r = 0; r < 16; r += 4)
                l_part += (p[r] + p[r + 1]) + (p[r + 2] + p[r + 3]);

            // pack pairs; u[g] covers kv pair base 8*(g>>1) + 2*(g&1) + 4*half
            unsigned int u[8], x[8];
#pragma unroll
            for (int g = 0; g < 8; ++g) u[g] = pk_rne(p[2 * g], p[2 * g + 1]);
#pragma unroll
            for (int g = 0; g < 8; ++g) x[g] = (unsigned int)__shfl_xor((int)u[g], 32);

            // PV: O^T[d][q] += V^T[d][kv] * P[q][kv]
#pragma unroll
            for (int c = 0; c < 2; ++c) {
                uint4 pd;
                pd.x = half ? x[4 * c + 2] : u[4 * c];
                pd.y = half ? x[4 * c + 3] : u[4 * c + 1];
                pd.z = half ? u[4 * c + 2] : x[4 * c];
                pd.w = half ? u[4 * c + 3] : x[4 * c + 1];
                union { uint4 i; bf16x8 v; } pf; pf.i = pd;
                const int cg = mt * 2 + c;                    // global 16-kv chunk
#pragma unroll
                for (int dm = 0; dm < 2; ++dm) {
                    const int drow = dm * 32 + q31;
                    bf16x8 vf = *reinterpret_cast<const bf16x8*>(
                        Vs + drow * 128 + (((cg * 2 + half) ^ (drow & 7)) * 8));
                    o_acc[dm] = __builtin_amdgcn_mfma_f32_32x32x16_bf16(vf, pf.v, o_acc[dm], 0, 0, 0);
                }
            }
        }
    }

    // l(q) = own half + partner half; q = lane-resident (col of O^T)
    const float l = l_part + __shfl_xor(l_part, 32);
    const float linv = __builtin_amdgcn_rcpf(l);

    // store O[q][d]: o_acc[dm] reg r -> d = dm*32 + (r&3) + 8*(r>>2) + 4*half
    const int q = q0 + wid * 32 + q31;
    unsigned short* orow = outp + ((size_t)(b * S_LEN + q)) * D_MODEL + h * HEAD_DIM;
#pragma unroll
    for (int dm = 0; dm < 2; ++dm)
#pragma unroll
        for (int g = 0; g < 8; ++g) {
            const int d = dm * 32 + 8 * (g >> 1) + 2 * (g & 1) + 4 * half;
            *reinterpret_cast<unsigned int*>(orow + d) =
                pk_rne(o_acc[dm][2 * g] * linv, o_acc[dm][2 * g + 1] * linv);
        }
}

extern "C" void kernel_launch(void* const* d_in, const int* in_sizes, int n_in,
                              void* d_out, int out_size, void* d_ws, size_t ws_size,
                              hipStream_t stream) {
    (void)in_sizes; (void)n_in; (void)out_size; (void)ws_size;
    const float* q  = (const float*)d_in[0];
    const float* k  = (const float*)d_in[1];
    const float* v  = (const float*)d_in[2];
    // d_in[3] = mask: mathematical no-op in the reference
    const float* Wq = (const float*)d_in[4];
    const float* bq = (const float*)d_in[5];
    const float* Wk = (const float*)d_in[6];
    const float* bk = (const float*)d_in[7];
    const float* Wv = (const float*)d_in[8];
    const float* bv = (const float*)d_in[9];
    const float* Wo = (const float*)d_in[10];
    const float* bo = (const float*)d_in[11];
    float* out = (float*)d_out;

    char* ws = (char*)d_ws;
    const size_t SZ_ACT = (size_t)BATCH * S_LEN * D_MODEL * 2;  // 8 MB
    const size_t SZ_W   = (size_t)D_MODEL * D_MODEL * 2;        // 2 MB
    unsigned short* qb   = (unsigned short*)(ws);
    unsigned short* kb   = (unsigned short*)(ws + SZ_ACT);
    unsigned short* vb   = (unsigned short*)(ws + 2 * SZ_ACT);
    unsigned short* Wqt  = (unsigned short*)(ws + 3 * SZ_ACT);
    unsigned short* Wkt  = (unsigned short*)(ws + 3 * SZ_ACT + SZ_W);
    unsigned short* Wvt  = (unsigned short*)(ws + 3 * SZ_ACT + 2 * SZ_W);
    unsigned short* Wot  = (unsigned short*)(ws + 3 * SZ_ACT + 3 * SZ_W);
    unsigned short* qhb  = (unsigned short*)(ws + 3 * SZ_ACT + 4 * SZ_W);
    unsigned short* khb  = (unsigned short*)(ws + 4 * SZ_ACT + 4 * SZ_W);
    unsigned short* vtb  = (unsigned short*)(ws + 5 * SZ_ACT + 4 * SZ_W);
    unsigned short* attn = qb;  // qb dead after Q projection

    PrepArgs pargs;
    pargs.src[0] = q;  pargs.src[1] = k;  pargs.src[2] = v;
    pargs.dst[0] = qb; pargs.dst[1] = kb; pargs.dst[2] = vb;
    pargs.W[0] = Wq;  pargs.W[1] = Wk;  pargs.W[2] = Wv;  pargs.W[3] = Wo;
    pargs.Wt[0] = Wqt; pargs.Wt[1] = Wkt; pargs.Wt[2] = Wvt; pargs.Wt[3] = Wot;
    prep_kernel<<<dim3(CONV_BLOCKS + 1024), 256, 0, stream>>>(pargs);

    QKVArgs gargs;
    gargs.A[0] = qb;  gargs.A[1] = kb;  gargs.A[2] = vb;
    gargs.Bt[0] = Wqt; gargs.Bt[1] = Wkt; gargs.Bt[2] = Wvt;
    gargs.bias[0] = bq; gargs.bias[1] = bk; gargs.bias[2] = bv;
    gargs.out[0] = qhb; gargs.out[1] = khb; gargs.out[2] = vtb;
    qkv_gemm_kernel<<<dim3(8, 32, 3), 256, 0, stream>>>(gargs);

    attn_kernel<<<dim3(S_LEN / 128, N_HEADS, BATCH), 256, 0, stream>>>(qhb, khb, vtb, attn);

    oproj_gemm_kernel<<<dim3(8, 64), 256, 0, stream>>>(attn, Wot, bo, out);
}